// Round 10
// baseline (357.200 us; speedup 1.0000x reference)
//
#include <hip/hip_runtime.h>

typedef unsigned short ushort_t;
typedef __attribute__((ext_vector_type(8))) short short8;
typedef __attribute__((ext_vector_type(8))) __bf16 bf16x8;
typedef __attribute__((ext_vector_type(4))) float floatx4;

#define NN 96
#define DD 64
#define BSZ 16
#define TSTEP 12
#define ITILES 6
#define NTILE (BSZ*ITILES)   /* 96 tiles */
#define JS 4                 /* j-splits per tile */
#define JPB 24               /* j's per block */

// workspace offsets (bytes)
#define OFF_HALL  0u           /* 13 slots * 393216 = 5111808 (slot 0 unused) */
#define OFF_E     5111808u     /* 73728 */
#define OFF_SG    5185536u     /* 2 parity slots * 393216 = 786432 */
#define OFF_RG    5971968u     /* 786432 */
#define OFF_PART  6758400u     /* 96*4*1024*4 = 1572864 */
#define OFF_WSWZ  8331264u     /* 73728 */
#define OFF_FLAGA 8404992u     /* 12*96*4*4 = 18432 */
#define OFF_FLAGB 8423424u     /* 12*96*4 = 4608 */
#define HSLOT     98304        /* floats per hidden/S/R slot */

union fragU  { short8 s; bf16x8 b; };
union packU  { floatx4 f; unsigned long long u[2]; };

static __device__ __forceinline__ short f2bf(float f){
    union { float f; unsigned u; } v; v.f = f;
    unsigned u = v.u;
    u += 0x7fffu + ((u >> 16) & 1u);   // RNE
    return (short)(u >> 16);
}
// inputs provably bounded (|h|<=1, 0.05-scale weights) -> no clamps needed
static __device__ __forceinline__ float fast_tanh(float x){
    float p = __expf(2.f * x);
    return (p - 1.f) * __builtin_amdgcn_rcpf(p + 1.f);
}
static __device__ __forceinline__ float fast_sigmoid(float x){
    float p = __expf(-x);
    return __builtin_amdgcn_rcpf(1.f + p);
}
static __device__ __forceinline__ void zero4(floatx4* a){
    floatx4 z = {0.f,0.f,0.f,0.f};
    a[0]=z; a[1]=z; a[2]=z; a[3]=z;
}
// agent-scope (device-coherent) 16B load/store — R6-validated handoff primitive
static __device__ __forceinline__ floatx4 aload4(const float* p){
    const unsigned long long* s = (const unsigned long long*)p;
    packU pk;
    pk.u[0] = __hip_atomic_load(s,     __ATOMIC_RELAXED, __HIP_MEMORY_SCOPE_AGENT);
    pk.u[1] = __hip_atomic_load(s + 1, __ATOMIC_RELAXED, __HIP_MEMORY_SCOPE_AGENT);
    return pk.f;
}
static __device__ __forceinline__ void astore4(float* p, floatx4 v){
    unsigned long long* d = (unsigned long long*)p;
    packU pk; pk.f = v;
    __hip_atomic_store(d,     pk.u[0], __ATOMIC_RELAXED, __HIP_MEMORY_SCOPE_AGENT);
    __hip_atomic_store(d + 1, pk.u[1], __ATOMIC_RELAXED, __HIP_MEMORY_SCOPE_AGENT);
}
// read A-fragments (16x64, row m = lane&15, k = quad*8+jj) from LDS tile stride 68
static __device__ __forceinline__ void buildA(const float* sM, int col, int quad, short8& a0, short8& a1){
    floatx4 f0 = *(const floatx4*)&sM[col*68 + quad*8];
    floatx4 f1 = *(const floatx4*)&sM[col*68 + quad*8 + 4];
    floatx4 f2 = *(const floatx4*)&sM[col*68 + 32 + quad*8];
    floatx4 f3 = *(const floatx4*)&sM[col*68 + 32 + quad*8 + 4];
    fragU u0, u1;
    #pragma unroll
    for (int jj = 0; jj < 4; jj++){
        u0.b[jj]   = (__bf16)f0[jj];
        u0.b[4+jj] = (__bf16)f1[jj];
        u1.b[jj]   = (__bf16)f2[jj];
        u1.b[4+jj] = (__bf16)f3[jj];
    }
    a0 = u0.s; a1 = u1.s;
}
// 16x64 = (16x64) @ (64x64), B pre-swizzled fragment-major
static __device__ __forceinline__ void mm16(short8 a0, short8 a1, const short8* wzm, int l, floatx4* acc){
    #pragma unroll
    for (int nt = 0; nt < 4; nt++){
        short8 b0 = wzm[nt*64 + l];
        short8 b1 = wzm[(4 + nt)*64 + l];
        acc[nt] = __builtin_amdgcn_mfma_f32_16x16x32_bf16(a0, b0, acc[nt], 0, 0, 0);
        acc[nt] = __builtin_amdgcn_mfma_f32_16x16x32_bf16(a1, b1, acc[nt], 0, 0, 0);
    }
}
// mm16 with preloaded B fragments
static __device__ __forceinline__ void mm16r(short8 a0, short8 a1, const short8* f, floatx4* acc){
    #pragma unroll
    for (int nt = 0; nt < 4; nt++){
        acc[nt] = __builtin_amdgcn_mfma_f32_16x16x32_bf16(a0, f[nt],     acc[nt], 0, 0, 0);
        acc[nt] = __builtin_amdgcn_mfma_f32_16x16x32_bf16(a1, f[4 + nt], acc[nt], 0, 0, 0);
    }
}

// ---------------------------------------------------------------------------
// init: zero flags, compute E_* = emb @ W_i* + b_*, pre-swizzle 9 weight
// matrices into bf16 B-fragment order. grid 216 = 72(E) + 144(swizzle).
// ---------------------------------------------------------------------------
__global__ __launch_bounds__(256) void k_init(
    const float* __restrict__ emb, const float* __restrict__ Wmsg1,
    const float* __restrict__ Wmsg2,
    const float* __restrict__ Whr, const float* __restrict__ Whi, const float* __restrict__ Whh,
    const float* __restrict__ Wir, const float* __restrict__ bir,
    const float* __restrict__ Wii, const float* __restrict__ bii,
    const float* __restrict__ Win, const float* __restrict__ bin,
    const float* __restrict__ Wo1, const float* __restrict__ Wo2, const float* __restrict__ Wo3,
    int* __restrict__ flags, float* __restrict__ Ef, ushort_t* __restrict__ wswz)
{
    int wg = blockIdx.x, tid = threadIdx.x;
    if (wg < 72) {                        // E matrices: 3 * 96 * 64
        int flat = wg*256 + tid;
        int m = flat / 6144; int r = flat % 6144; int s = r >> 6; int d = r & 63;
        const float* W = (m==0)? Wir : (m==1)? Wii : Win;
        const float* B = (m==0)? bir : (m==1)? bii : bin;
        float acc = B[d];
        #pragma unroll 8
        for (int k = 0; k < 64; k++)
            acc += emb[s*64 + k] * W[k*64 + d];
        Ef[flat] = acc;
        if (wg < 23) {                    // zero flagA(4608) + flagB(1152), contiguous
            int c = wg*256 + tid;
            if (c < 5760) flags[c] = 0;
        }
    } else {                              // swizzle: 9 * 4096
        int flat = (wg - 72)*256 + tid;
        int m = flat >> 12; int q = flat & 4095;
        int jj = q & 7, lane = (q >> 3) & 63, nt = (q >> 9) & 3, kc = q >> 11;
        int k = kc*32 + ((lane >> 4) << 3) + jj;
        int n = nt*16 + (lane & 15);
        const float* src; int idx = k*64 + n;
        switch (m) {
          case 0: src = Wmsg2; break;
          case 1: src = Whr;  break;
          case 2: src = Whi;  break;
          case 3: src = Whh;  break;
          case 4: src = Wmsg1; break;
          case 5: src = Wmsg1; idx = (64 + k)*64 + n; break;
          case 6: src = Wo1; break;
          case 7: src = Wo2; break;
          default: src = Wo3; break;
        }
        wswz[flat] = (ushort_t)f2bf(src[idx]);
    }
}

// ---------------------------------------------------------------------------
// persistent kernel, grid 384 = 96 tiles x 4 j-splits, 512 threads.
// Block (b,it,js) handles j = js*24 .. js*24+23 for its 16-row tile.
// Per step: msg (8 waves x 3 j's) -> LDS-reduce -> partial.
//   js>0: agent-store partial, flag A, then wait flag B + reload S/R.
//   js0 : collect 3 partials (flag A spin), block-local GRU (h resident in
//         LDS all steps), publish raw S/R (agent) + flag B, write hall[t+1].
// Co-residency: LDS 51.8KB (2 blocks/CU), VGPR capped by bounds(512,4)
// -> all 384 blocks resident; spins cannot deadlock. No fences anywhere.
// S/R parity double-buffered (safety chain: flagA(t) => all flagB(t-1) =>
// every block of batch b done reading S(t-1) before slot reuse).
// ---------------------------------------------------------------------------
__global__ __launch_bounds__(512, 4) void k_all(
    const float* __restrict__ adj, const float* __restrict__ b1in, const float* __restrict__ b2in,
    const int* __restrict__ skills, const float* __restrict__ Ef,
    const ushort_t* __restrict__ wswz,
    float* __restrict__ Pbuf, float* __restrict__ Sg, float* __restrict__ Rg,
    float* __restrict__ hall, int* __restrict__ flagA, int* __restrict__ flagB)
{
    __shared__ float lds[12944];
    float* sAdj = lds;            // 16 x 25 = 400 (padded)
    float* sS   = lds + 400;      // 24 x 64 = 1536
    float* sRB  = lds + 1936;     // 16 x 68 = 1088 (R + b1)
    float* sH   = lds + 3024;     // 16 x 64 = 1024 (js0: resident h tile)
    float* sE   = lds + 4048;     // 192
    float* sAgg = lds + 4240;     // 8 x 1088 = 8704
    float* sM   = sAgg;           // slice 0 (reduced agg, then hnew)
    float* sG   = sAgg + 1088;    // slices 1..3 (gate outputs)

    int wg = blockIdx.x;
    int tile = wg >> 2, js = wg & 3;
    int b = tile / 6, it = tile % 6;
    int tid = threadIdx.x; int w = tid >> 6; int l = tid & 63;
    int quad = l >> 4, col = l & 15;
    int j0 = js * JPB;
    int ta = j0 >> 4, tb = (j0 + JPB - 1) >> 4;   // tiles spanned by my j-range

    // ---- one-time prelude ----
    if (tid < 384) {
        int i = tid / 24, j = tid % 24;
        sAdj[i*25 + j] = adj[(b*NN + it*16 + i)*NN + j0 + j];
    }
    const short8* wz = (const short8*)wswz;   // matrix 0 = Wmsg2
    short8 w2f[2][4];
    #pragma unroll
    for (int kc = 0; kc < 2; kc++)
      #pragma unroll
      for (int nt = 0; nt < 4; nt++)
        w2f[kc][nt] = wz[(kc*4 + nt)*64 + l];
    float b2v[4], b1v[4];
    #pragma unroll
    for (int nt = 0; nt < 4; nt++) {
        b2v[nt] = b2in[nt*16 + col];
        b1v[nt] = b1in[nt*16 + col];
    }
    short8 fG[8], fSR[8];
    if (js == 0) {
        if (w < 3) {
            #pragma unroll
            for (int q = 0; q < 8; q++) fG[q] = wz[(1 + w)*512 + q*64 + l];
        }
        if (w < 2) {
            #pragma unroll
            for (int q = 0; q < 8; q++) fSR[q] = wz[(4 + w)*512 + q*64 + l];
        }
    }
    // t=0 state: S=0, R=0 (sRB=b1), h=0
    for (int q = tid; q < JPB*64; q += 512) sS[q] = 0.f;
    for (int q = tid; q < 16*64; q += 512) {
        sRB[(q >> 6)*68 + (q & 63)] = b1in[q & 63];
        sH[q] = 0.f;
    }
    __syncthreads();

    int tile4 = tile*4;
    for (int t = 0; t < TSTEP; t++) {
        // ---- message + aggregate: wave w handles local j = w*3 + c ----
        float rbv[16];
        #pragma unroll
        for (int c = 0; c < 4; c++)
            *(floatx4*)&rbv[c*4] = *(const floatx4*)&sRB[col*68 + (c>>1)*32 + quad*8 + (c&1)*4];

        float agg[4][4];
        #pragma unroll
        for (int nt=0;nt<4;nt++)
          #pragma unroll
          for (int r=0;r<4;r++) agg[nt][r] = 0.f;

        for (int c = 0; c < 3; c++) {
            int jl = w*3 + c;
            float sv[16];
            #pragma unroll
            for (int cc = 0; cc < 4; cc++)
                *(floatx4*)&sv[cc*4] = *(const floatx4*)&sS[jl*64 + (cc>>1)*32 + quad*8 + (cc&1)*4];
            fragU u0, u1;
            #pragma unroll
            for (int e = 0; e < 8; e++) {
                u0.b[e] = (__bf16)fast_tanh(sv[e]   + rbv[e]);
                u1.b[e] = (__bf16)fast_tanh(sv[8+e] + rbv[8+e]);
            }
            floatx4 acc[4];
            zero4(acc);
            #pragma unroll
            for (int nt = 0; nt < 4; nt++) {
                acc[nt] = __builtin_amdgcn_mfma_f32_16x16x32_bf16(u0.s, w2f[0][nt], acc[nt], 0,0,0);
                acc[nt] = __builtin_amdgcn_mfma_f32_16x16x32_bf16(u1.s, w2f[1][nt], acc[nt], 0,0,0);
            }
            float adjv[4];
            #pragma unroll
            for (int r = 0; r < 4; r++) adjv[r] = sAdj[(quad*4 + r)*25 + jl];
            #pragma unroll
            for (int nt = 0; nt < 4; nt++)
              #pragma unroll
              for (int r = 0; r < 4; r++)
                agg[nt][r] += adjv[r] * fast_tanh(acc[nt][r] + b2v[nt]);
        }
        #pragma unroll
        for (int nt = 0; nt < 4; nt++)
          #pragma unroll
          for (int r = 0; r < 4; r++)
            sAgg[w*1088 + (quad*4 + r)*68 + nt*16 + col] = agg[nt][r];
        __syncthreads();

        // ---- reduce 8 slices (scaled); js>0 -> agent partial, js0 -> sM ----
        if (tid < 256) {
            floatx4 a = {0.f,0.f,0.f,0.f};
            int i = tid >> 4, k4 = (tid & 15)*4;
            #pragma unroll
            for (int s8 = 0; s8 < 8; s8++)
                a += *(const floatx4*)&sAgg[s8*1088 + i*68 + k4];
            a = a * (1.f/96.f);
            if (js) astore4(&Pbuf[(tile4 + js)*1024 + tid*4], a);
            else    *(floatx4*)&sM[i*68 + k4] = a;
        } else if (js == 0 && tid < 448) {
            int q = tid - 256;
            int s = skills[b*13 + t];
            sE[q] = Ef[(q >> 6)*6144 + s*64 + (q & 63)];
        }
        __syncthreads();                  // drains agent stores (vmcnt 0)

        if (js) {
            if (tid == 0)
                __hip_atomic_store(&flagA[(t*NTILE + tile)*4 + js], 1,
                                   __ATOMIC_RELAXED, __HIP_MEMORY_SCOPE_AGENT);
            if (t == TSTEP - 1) return;
        } else {
            // ---- collect 3 peer partials ----
            if (tid < 3) {
                const int* fp = &flagA[(t*NTILE + tile)*4 + tid + 1];
                while (__hip_atomic_load(fp, __ATOMIC_RELAXED, __HIP_MEMORY_SCOPE_AGENT) == 0)
                    __builtin_amdgcn_s_sleep(2);
            }
            __syncthreads();
            if (tid < 256) {
                int i = tid >> 4, k4 = (tid & 15)*4;
                floatx4 a = *(const floatx4*)&sM[i*68 + k4];
                #pragma unroll
                for (int p = 1; p < JS; p++)
                    a += aload4(&Pbuf[(tile4 + p)*1024 + tid*4]);
                *(floatx4*)&sM[i*68 + k4] = a;
            }
            __syncthreads();

            // ---- gates: wave w -> Whr/Whi/Whh ----
            if (w < 3) {
                short8 a0, a1;
                buildA(sM, col, quad, a0, a1);
                floatx4 acc[4];
                zero4(acc);
                mm16r(a0, a1, fG, acc);
                #pragma unroll
                for (int nt = 0; nt < 4; nt++)
                  #pragma unroll
                  for (int r = 0; r < 4; r++)
                    sG[w*1088 + (quad*4 + r)*68 + nt*16 + col] = acc[nt][r];
            }
            __syncthreads();

            // ---- elementwise GRU: h resident in sH; hall[t+1] normal store ----
            if (tid < 256) {
                int i = tid >> 4, k4 = (tid & 15)*4;
                float h[4];
                #pragma unroll
                for (int e = 0; e < 4; e++) {
                    int d = k4 + e;
                    float gr = fast_sigmoid(sE[d]       + sG[0*1088 + i*68 + d]);
                    float gi = fast_sigmoid(sE[64 + d]  + sG[1*1088 + i*68 + d]);
                    float nv = fast_tanh  (sE[128 + d] + gr * sG[2*1088 + i*68 + d]);
                    h[e] = (1.f - gi)*nv + gi*sH[i*64 + d];
                }
                #pragma unroll
                for (int e = 0; e < 4; e++) {
                    sH[i*64 + k4 + e] = h[e];
                    sM[i*68 + k4 + e] = h[e];
                }
                floatx4 hv = { h[0], h[1], h[2], h[3] };
                *(floatx4*)&hall[(size_t)(t+1)*HSLOT + (b*NN + it*16 + i)*64 + k4] = hv;
            }
            __syncthreads();
            if (t == TSTEP - 1) return;

            // ---- projections: wave0 -> S (agent), wave1 -> R (agent + local) ----
            int p = (t + 1) & 1;
            if (w < 2) {
                short8 a0, a1;
                buildA(sM, col, quad, a0, a1);
                floatx4 acc[4];
                zero4(acc);
                mm16r(a0, a1, fSR, acc);
                float* dst = ((w == 0) ? Sg : Rg) + (size_t)p*HSLOT;
                #pragma unroll
                for (int nt = 0; nt < 4; nt++)
                  #pragma unroll
                  for (int r = 0; r < 4; r++) {
                    int addr = (b*NN + it*16 + quad*4 + r)*64 + nt*16 + col;
                    __hip_atomic_store(&dst[addr], acc[nt][r],
                                       __ATOMIC_RELAXED, __HIP_MEMORY_SCOPE_AGENT);
                    if (w == 1)
                        sRB[(quad*4 + r)*68 + nt*16 + col] = acc[nt][r] + b1v[nt];
                  }
            }
            __syncthreads();              // drain winner agent stores
            if (tid == 0)
                __hip_atomic_store(&flagB[t*NTILE + tile], 1,
                                   __ATOMIC_RELAXED, __HIP_MEMORY_SCOPE_AGENT);
        }

        // ---- wait for producer tiles, reload S (all) and R (js>0) ----
        {
            int p = (t + 1) & 1;
            if (tid < 3) {
                int tf = (tid == 0) ? ta : (tid == 1) ? tb : (js ? it : ta);
                const int* fp = &flagB[t*NTILE + b*ITILES + tf];
                while (__hip_atomic_load(fp, __ATOMIC_RELAXED, __HIP_MEMORY_SCOPE_AGENT) == 0)
                    __builtin_amdgcn_s_sleep(2);
            }
            __syncthreads();
            if (tid < 384) {
                int row = tid >> 4, c4 = (tid & 15)*4;
                *(floatx4*)&sS[row*64 + c4] =
                    aload4(&Sg[(size_t)p*HSLOT + (b*NN + j0 + row)*64 + c4]);
            }
            if (js && tid < 256) {
                int i = tid >> 4, k4 = (tid & 15)*4;
                floatx4 r4 = aload4(&Rg[(size_t)p*HSLOT + (b*NN + it*16 + i)*64 + k4]);
                floatx4 b4 = *(const floatx4*)&b1in[k4];
                *(floatx4*)&sRB[i*68 + k4] = r4 + b4;
            }
            __syncthreads();
        }
    }
}

// ---------------------------------------------------------------------------
// batched output MLP over all steps: 1152 independent 16-row tiles, 4 waves
// per block (one tile each, private LDS slice, no barriers). Reads hall
// slots 1..12 (k_all produced h(12) too). grid 288 x 256 threads.
// ---------------------------------------------------------------------------
__global__ __launch_bounds__(256) void k_out(
    const float* __restrict__ hall, const ushort_t* __restrict__ wswz,
    const float* __restrict__ bo1, const float* __restrict__ bo2, const float* __restrict__ bo3,
    float* __restrict__ out)
{
    __shared__ float sT[4][16*68];
    int tid = threadIdx.x; int w = tid >> 6; int l = tid & 63;
    int quad = l >> 4, col = l & 15;
    int g = blockIdx.x*4 + w;
    int ts = g / 96; int rem = g % 96; int b = rem / 6, it = rem % 6;
    float* sm = sT[w];
    {
        const float* hsrc = hall + (size_t)(ts + 1)*HSLOT + (b*NN + it*16)*64;
        int i = l >> 2, c0 = (l & 3)*16;
        #pragma unroll
        for (int cc = 0; cc < 4; cc++)
            *(floatx4*)&sm[i*68 + c0 + cc*4] = *(const floatx4*)&hsrc[i*64 + c0 + cc*4];
    }
    float bv1[4], bv2[4], bv3[4];
    #pragma unroll
    for (int nt = 0; nt < 4; nt++) {
        bv1[nt] = bo1[nt*16 + col];
        bv2[nt] = bo2[nt*16 + col];
        bv3[nt] = bo3[nt*16 + col];
    }
    short8 a0, a1;
    floatx4 acc[4];

    buildA(sm, col, quad, a0, a1);
    zero4(acc);
    mm16(a0, a1, (const short8*)wswz + 6*512, l, acc);
    #pragma unroll
    for (int nt = 0; nt < 4; nt++)
      #pragma unroll
      for (int r = 0; r < 4; r++)
        sm[(quad*4 + r)*68 + nt*16 + col] = fmaxf(0.f, acc[nt][r] + bv1[nt]);

    buildA(sm, col, quad, a0, a1);
    zero4(acc);
    mm16(a0, a1, (const short8*)wswz + 7*512, l, acc);
    #pragma unroll
    for (int nt = 0; nt < 4; nt++)
      #pragma unroll
      for (int r = 0; r < 4; r++)
        sm[(quad*4 + r)*68 + nt*16 + col] = fmaxf(0.f, acc[nt][r] + bv2[nt]);

    buildA(sm, col, quad, a0, a1);
    zero4(acc);
    mm16(a0, a1, (const short8*)wswz + 8*512, l, acc);
    #pragma unroll
    for (int nt = 0; nt < 4; nt++)
      #pragma unroll
      for (int r = 0; r < 4; r++)
        out[((b*TSTEP + ts)*NN + it*16 + quad*4 + r)*64 + nt*16 + col] = acc[nt][r] + bv3[nt];
}

extern "C" void kernel_launch(void* const* d_in, const int* in_sizes, int n_in,
                              void* d_out, int out_size, void* d_ws, size_t ws_size,
                              hipStream_t stream) {
    const int*   skills = (const int*)d_in[0];
    const float* adj    = (const float*)d_in[1];
    const float* emb    = (const float*)d_in[2];
    const float* Wmsg1  = (const float*)d_in[3];
    const float* b1     = (const float*)d_in[4];
    const float* Wmsg2  = (const float*)d_in[5];
    const float* b2     = (const float*)d_in[6];
    const float* Whr    = (const float*)d_in[7];
    const float* Whi    = (const float*)d_in[8];
    const float* Whh    = (const float*)d_in[9];
    const float* Wir    = (const float*)d_in[10];
    const float* bir    = (const float*)d_in[11];
    const float* Wii    = (const float*)d_in[12];
    const float* bii    = (const float*)d_in[13];
    const float* Win    = (const float*)d_in[14];
    const float* bin    = (const float*)d_in[15];
    const float* Wo1    = (const float*)d_in[16];
    const float* bo1    = (const float*)d_in[17];
    const float* Wo2    = (const float*)d_in[18];
    const float* bo2    = (const float*)d_in[19];
    const float* Wo3    = (const float*)d_in[20];
    const float* bo3    = (const float*)d_in[21];

    char* ws = (char*)d_ws;
    float*    hall  = (float*)(ws + OFF_HALL);
    float*    Ef    = (float*)(ws + OFF_E);
    float*    Sg    = (float*)(ws + OFF_SG);
    float*    Rg    = (float*)(ws + OFF_RG);
    float*    Pbuf  = (float*)(ws + OFF_PART);
    ushort_t* wswz  = (ushort_t*)(ws + OFF_WSWZ);
    int*      flagA = (int*)(ws + OFF_FLAGA);
    int*      flagB = (int*)(ws + OFF_FLAGB);
    float*    out   = (float*)d_out;

    k_init<<<dim3(216), dim3(256), 0, stream>>>(emb, Wmsg1, Wmsg2, Whr, Whi, Whh,
        Wir, bir, Wii, bii, Win, bin, Wo1, Wo2, Wo3, flagA, Ef, wswz);

    k_all<<<dim3(NTILE*JS), dim3(512), 0, stream>>>(
        adj, b1, b2, skills, Ef, wswz, Pbuf, Sg, Rg, hall, flagA, flagB);

    k_out<<<dim3(288), dim3(256), 0, stream>>>(hall, wswz, bo1, bo2, bo3, out);
}

// Round 11
// 252.375 us; speedup vs baseline: 1.4154x; 1.4154x over previous
//
#include <hip/hip_runtime.h>

typedef unsigned short ushort_t;
typedef __attribute__((ext_vector_type(8))) short short8;
typedef __attribute__((ext_vector_type(8))) __bf16 bf16x8;
typedef __attribute__((ext_vector_type(4))) float floatx4;

#define NN 96
#define DD 64
#define BSZ 16
#define TSTEP 12
#define JSPLIT 8
#define JPW 12   /* 96 / JSPLIT */
#define ITILES 6

// workspace offsets (bytes)
#define OFF_HALL  0u           /* 13 slots * 393216 = 5111808 (slot 0 unused) */
#define OFF_E     5111808u     /* 73728 */
#define OFF_S0    5185536u     /* 393216 */
#define OFF_S1    5578752u     /* 393216 */
#define OFF_R0    5971968u     /* 393216 */
#define OFF_R1    6365184u     /* 393216 */
#define OFF_PART  6758400u     /* 8*393216 = 3145728 */
#define OFF_WSWZ  9904128u     /* 73728 */
#define OFF_CNT   9977856u     /* 12*96*4 = 4608 */
#define HSLOT     98304        /* floats per hidden slot */

union fragU  { short8 s; bf16x8 b; };
union packU  { floatx4 f; unsigned long long u[2]; };

static __device__ __forceinline__ short f2bf(float f){
    union { float f; unsigned u; } v; v.f = f;
    unsigned u = v.u;
    u += 0x7fffu + ((u >> 16) & 1u);   // RNE
    return (short)(u >> 16);
}
// inputs provably bounded (|h|<=1, 0.05-scale weights) -> no clamps needed
static __device__ __forceinline__ float fast_tanh(float x){
    float p = __expf(2.f * x);
    return (p - 1.f) * __builtin_amdgcn_rcpf(p + 1.f);
}
static __device__ __forceinline__ float fast_sigmoid(float x){
    float p = __expf(-x);
    return __builtin_amdgcn_rcpf(1.f + p);
}
static __device__ __forceinline__ void zero4(floatx4* a){
    floatx4 z = {0.f,0.f,0.f,0.f};
    a[0]=z; a[1]=z; a[2]=z; a[3]=z;
}
// agent-scope (device-coherent) 16B load/store — R6-validated handoff primitive
static __device__ __forceinline__ floatx4 aload4(const float* p){
    const unsigned long long* s = (const unsigned long long*)p;
    packU pk;
    pk.u[0] = __hip_atomic_load(s,     __ATOMIC_RELAXED, __HIP_MEMORY_SCOPE_AGENT);
    pk.u[1] = __hip_atomic_load(s + 1, __ATOMIC_RELAXED, __HIP_MEMORY_SCOPE_AGENT);
    return pk.f;
}
static __device__ __forceinline__ void astore4(float* p, floatx4 v){
    unsigned long long* d = (unsigned long long*)p;
    packU pk; pk.f = v;
    __hip_atomic_store(d,     pk.u[0], __ATOMIC_RELAXED, __HIP_MEMORY_SCOPE_AGENT);
    __hip_atomic_store(d + 1, pk.u[1], __ATOMIC_RELAXED, __HIP_MEMORY_SCOPE_AGENT);
}
// read A-fragments (16x64, row m = lane&15, k = quad*8+jj) from LDS tile stride 68
static __device__ __forceinline__ void buildA(const float* sM, int col, int quad, short8& a0, short8& a1){
    floatx4 f0 = *(const floatx4*)&sM[col*68 + quad*8];
    floatx4 f1 = *(const floatx4*)&sM[col*68 + quad*8 + 4];
    floatx4 f2 = *(const floatx4*)&sM[col*68 + 32 + quad*8];
    floatx4 f3 = *(const floatx4*)&sM[col*68 + 32 + quad*8 + 4];
    fragU u0, u1;
    #pragma unroll
    for (int jj = 0; jj < 4; jj++){
        u0.b[jj]   = (__bf16)f0[jj];
        u0.b[4+jj] = (__bf16)f1[jj];
        u1.b[jj]   = (__bf16)f2[jj];
        u1.b[4+jj] = (__bf16)f3[jj];
    }
    a0 = u0.s; a1 = u1.s;
}
// 16x64 = (16x64) @ (64x64), B pre-swizzled fragment-major
static __device__ __forceinline__ void mm16(short8 a0, short8 a1, const short8* wzm, int l, floatx4* acc){
    #pragma unroll
    for (int nt = 0; nt < 4; nt++){
        short8 b0 = wzm[nt*64 + l];
        short8 b1 = wzm[(4 + nt)*64 + l];
        acc[nt] = __builtin_amdgcn_mfma_f32_16x16x32_bf16(a0, b0, acc[nt], 0, 0, 0);
        acc[nt] = __builtin_amdgcn_mfma_f32_16x16x32_bf16(a1, b1, acc[nt], 0, 0, 0);
    }
}
// mm16 with preloaded B fragments
static __device__ __forceinline__ void mm16r(short8 a0, short8 a1, const short8* f, floatx4* acc){
    #pragma unroll
    for (int nt = 0; nt < 4; nt++){
        acc[nt] = __builtin_amdgcn_mfma_f32_16x16x32_bf16(a0, f[nt],     acc[nt], 0, 0, 0);
        acc[nt] = __builtin_amdgcn_mfma_f32_16x16x32_bf16(a1, f[4 + nt], acc[nt], 0, 0, 0);
    }
}

// ---------------------------------------------------------------------------
// init: zero counters, compute E_* = emb @ W_i* + b_*, pre-swizzle 9 weight
// matrices. grid 216 = 72(E) + 144(swizzle), 256 threads.
// (S0/R0/hall0 zeroing dropped: t=0 is collapsed into k_step0.)
// ---------------------------------------------------------------------------
__global__ __launch_bounds__(256) void k_init(
    const float* __restrict__ emb, const float* __restrict__ Wmsg1,
    const float* __restrict__ Wmsg2,
    const float* __restrict__ Whr, const float* __restrict__ Whi, const float* __restrict__ Whh,
    const float* __restrict__ Wir, const float* __restrict__ bir,
    const float* __restrict__ Wii, const float* __restrict__ bii,
    const float* __restrict__ Win, const float* __restrict__ bin,
    const float* __restrict__ Wo1, const float* __restrict__ Wo2, const float* __restrict__ Wo3,
    int* __restrict__ cnt, float* __restrict__ Ef, ushort_t* __restrict__ wswz)
{
    int wg = blockIdx.x, tid = threadIdx.x;
    if (wg < 72) {                        // E matrices: 3 * 96 * 64
        int flat = wg*256 + tid;
        int m = flat / 6144; int r = flat % 6144; int s = r >> 6; int d = r & 63;
        const float* W = (m==0)? Wir : (m==1)? Wii : Win;
        const float* B = (m==0)? bir : (m==1)? bii : bin;
        float acc = B[d];
        #pragma unroll 8
        for (int k = 0; k < 64; k++)
            acc += emb[s*64 + k] * W[k*64 + d];
        Ef[flat] = acc;
        if (wg < 5) {
            int c = wg*256 + tid;
            if (c < TSTEP*BSZ*ITILES) cnt[c] = 0;
        }
    } else {                              // swizzle: 9 * 4096
        int flat = (wg - 72)*256 + tid;
        int m = flat >> 12; int q = flat & 4095;
        int jj = q & 7, lane = (q >> 3) & 63, nt = (q >> 9) & 3, kc = q >> 11;
        int k = kc*32 + ((lane >> 4) << 3) + jj;
        int n = nt*16 + (lane & 15);
        const float* src; int idx = k*64 + n;
        switch (m) {
          case 0: src = Wmsg2; break;
          case 1: src = Whr;  break;
          case 2: src = Whi;  break;
          case 3: src = Whh;  break;
          case 4: src = Wmsg1; break;
          case 5: src = Wmsg1; idx = (64 + k)*64 + n; break;
          case 6: src = Wo1; break;
          case 7: src = Wo2; break;
          default: src = Wo3; break;
        }
        wswz[flat] = (ushort_t)f2bf(src[idx]);
    }
}

// ---------------------------------------------------------------------------
// step 0 (collapsed): at t=0, S=R=0 so every edge message equals
// msgv = tanh(tanh(b1)@Wmsg2 + b2) and agg[i] = rowsum(adj[i])/96 * msgv.
// One block per tile (96 x 256): rowsum + msgv -> GRU(0) with h=0 ->
// h(1) -> hall[1], S(1)->S1, R(1)->R1 (normal stores; consumed next dispatch).
// ---------------------------------------------------------------------------
__global__ __launch_bounds__(256) void k_step0(
    const float* __restrict__ adj, const float* __restrict__ b1in, const float* __restrict__ b2in,
    const int* __restrict__ skills, const float* __restrict__ Ef,
    const ushort_t* __restrict__ wswz,
    float* __restrict__ hall, float* __restrict__ S1, float* __restrict__ R1)
{
    __shared__ float sM[16*68];
    __shared__ float sG[3][16*68];
    __shared__ float sE[3*64];
    __shared__ float sRS[16*17];
    int wg = blockIdx.x; int b = wg / 6, it = wg % 6;
    int tid = threadIdx.x; int w = tid >> 6; int l = tid & 63;
    int quad = l >> 4, col = l & 15;

    {   // rowsum(adj): thread (i, seg) sums 6 j's; reduce 16 partials per row
        int i = tid >> 4, seg = tid & 15;
        const float* arow = &adj[(b*NN + it*16 + i)*NN + seg*6];
        float s = 0.f;
        #pragma unroll
        for (int j = 0; j < 6; j++) s += arow[j];
        sRS[i*17 + seg] = s;
    }
    if (tid < 192) {
        int s = skills[b*13 + 0];
        sE[tid] = Ef[(tid >> 6)*6144 + s*64 + (tid & 63)];
    }
    __syncthreads();
    if (tid < 16) {
        float s = 0.f;
        #pragma unroll
        for (int q = 0; q < 16; q++) s += sRS[tid*17 + q];
        sRS[tid*17 + 16] = s * (1.f/96.f);
    }
    __syncthreads();

    // wave 0: msgv via the standard msg pipeline on broadcast rows, -> sM
    if (w == 0) {
        float b2v[4];
        #pragma unroll
        for (int nt = 0; nt < 4; nt++) b2v[nt] = b2in[nt*16 + col];
        fragU u0, u1;
        #pragma unroll
        for (int e = 0; e < 8; e++) {
            u0.b[e] = (__bf16)fast_tanh(b1in[quad*8 + e]);        // k = quad*8+e
            u1.b[e] = (__bf16)fast_tanh(b1in[32 + quad*8 + e]);   // k = 32+quad*8+e
        }
        floatx4 acc[4];
        zero4(acc);
        mm16(u0.s, u1.s, (const short8*)wswz + 0*512, l, acc);
        #pragma unroll
        for (int nt = 0; nt < 4; nt++)
          #pragma unroll
          for (int r = 0; r < 4; r++) {
            float m = fast_tanh(acc[nt][r] + b2v[nt]);            // row-independent
            sM[(quad*4 + r)*68 + nt*16 + col] = sRS[(quad*4 + r)*17 + 16] * m;
          }
    }
    __syncthreads();

    // gates: wave w -> Whr/Whi/Whh
    if (w < 3) {
        short8 a0, a1;
        buildA(sM, col, quad, a0, a1);
        floatx4 acc[4];
        zero4(acc);
        mm16(a0, a1, (const short8*)wswz + (1 + w)*512, l, acc);
        #pragma unroll
        for (int nt = 0; nt < 4; nt++)
          #pragma unroll
          for (int r = 0; r < 4; r++)
            sG[w][(quad*4 + r)*68 + nt*16 + col] = acc[nt][r];
    }
    __syncthreads();

    // elementwise GRU with h_old = 0 -> h(1); write sM + hall[1]
    {
        int i = tid >> 4, k4 = (tid & 15)*4;
        float h[4];
        #pragma unroll
        for (int e = 0; e < 4; e++) {
            int d = k4 + e;
            float gi = fast_sigmoid(sE[64 + d] + sG[1][i*68 + d]);
            float gr = fast_sigmoid(sE[d]      + sG[0][i*68 + d]);
            float nv = fast_tanh  (sE[128 + d] + gr * sG[2][i*68 + d]);
            h[e] = (1.f - gi)*nv;
        }
        #pragma unroll
        for (int e = 0; e < 4; e++) sM[i*68 + k4 + e] = h[e];
        floatx4 hv = { h[0], h[1], h[2], h[3] };
        *(floatx4*)&hall[(size_t)1*HSLOT + (b*NN + it*16 + i)*64 + k4] = hv;
    }
    __syncthreads();

    // S (wave 0) / R (wave 1) projections -> S1 / R1
    if (w < 2) {
        short8 a0, a1;
        buildA(sM, col, quad, a0, a1);
        floatx4 acc[4];
        zero4(acc);
        mm16(a0, a1, (const short8*)wswz + (4 + w)*512, l, acc);
        float* dst = (w == 0) ? S1 : R1;
        #pragma unroll
        for (int nt = 0; nt < 4; nt++)
          #pragma unroll
          for (int r = 0; r < 4; r++)
            dst[(b*NN + it*16 + quad*4 + r)*64 + nt*16 + col] = acc[nt][r];
    }
}

// ---------------------------------------------------------------------------
// fused step t (t = 1..11): message+aggregate (R6 body, j-loop unrolled);
// partials agent-stored; last js-block per (b,it) runs the GRU in-place.
// S/R ping-pong by parity. t=11: msg only (GRU in k_out).
// grid 768 = 8(js) x 16(b) x 6(it), 256 threads.
// ---------------------------------------------------------------------------
__global__ __launch_bounds__(256) void k_step(
    const float* __restrict__ adj, const float* __restrict__ b1in, const float* __restrict__ b2in,
    const float* __restrict__ Sread, const float* __restrict__ Rread,
    const ushort_t* __restrict__ wswz, float* __restrict__ partial,
    const int* __restrict__ skills, const float* __restrict__ Ef,
    const float* __restrict__ hprev, float* __restrict__ hcur,
    float* __restrict__ Swrite, float* __restrict__ Rwrite,
    int* __restrict__ cnt, int t)
{
    __shared__ float lds[6400];
    __shared__ int sLast;
    float* sS   = lds;          // 12*64  = 768
    float* sRB  = lds + 768;    // 16*68  = 1088
    float* sAdj = lds + 1856;   // 16*12  = 192
    float* sAgg = lds + 2048;   // 4*1088 = 4352

    int wg = blockIdx.x;
    int js = wg / 96; int rem = wg % 96; int b = rem / 6; int it = rem % 6;
    int tid = threadIdx.x; int w = tid >> 6; int l = tid & 63;
    int quad = l >> 4, col = l & 15;
    int j0 = js * JPW;

    for (int q = tid; q < JPW*16; q += 256) {
        int row = q >> 4, c4 = (q & 15) * 4;
        *(floatx4*)&sS[row*64 + c4] = *(const floatx4*)&Sread[(b*NN + j0 + row)*64 + c4];
    }
    for (int q = tid; q < 16*16; q += 256) {
        int row = q >> 4, c4 = (q & 15) * 4;
        floatx4 r4 = *(const floatx4*)&Rread[(b*NN + it*16 + row)*64 + c4];
        floatx4 b4 = *(const floatx4*)&b1in[c4];
        floatx4 o = r4 + b4;
        *(floatx4*)&sRB[row*68 + c4] = o;
    }
    for (int q = tid; q < 16*JPW; q += 256) {
        int i = q / JPW, j = q % JPW;
        sAdj[q] = adj[(b*NN + it*16 + i)*NN + j0 + j];
    }
    const short8* wz = (const short8*)wswz;   // matrix 0 = Wmsg2
    short8 w2f[2][4];
    #pragma unroll
    for (int kc = 0; kc < 2; kc++)
      #pragma unroll
      for (int nt = 0; nt < 4; nt++)
        w2f[kc][nt] = wz[(kc*4 + nt)*64 + l];
    float b2v[4];
    #pragma unroll
    for (int nt = 0; nt < 4; nt++) b2v[nt] = b2in[nt*16 + col];
    __syncthreads();

    float rbv[16];
    #pragma unroll
    for (int c = 0; c < 4; c++)
        *(floatx4*)&rbv[c*4] = *(const floatx4*)&sRB[col*68 + (c>>1)*32 + quad*8 + (c&1)*4];

    float agg[4][4];
    #pragma unroll
    for (int nt=0;nt<4;nt++)
      #pragma unroll
      for (int r=0;r<4;r++) agg[nt][r] = 0.f;

    #pragma unroll
    for (int c = 0; c < 3; c++) {
        int jl = w*3 + c;
        float sv[16];
        #pragma unroll
        for (int cc = 0; cc < 4; cc++)
            *(floatx4*)&sv[cc*4] = *(const floatx4*)&sS[jl*64 + (cc>>1)*32 + quad*8 + (cc&1)*4];
        fragU u0, u1;
        #pragma unroll
        for (int e = 0; e < 8; e++) {
            u0.b[e] = (__bf16)fast_tanh(sv[e]   + rbv[e]);
            u1.b[e] = (__bf16)fast_tanh(sv[8+e] + rbv[8+e]);
        }
        floatx4 acc[4];
        zero4(acc);
        #pragma unroll
        for (int nt = 0; nt < 4; nt++) {
            acc[nt] = __builtin_amdgcn_mfma_f32_16x16x32_bf16(u0.s, w2f[0][nt], acc[nt], 0,0,0);
            acc[nt] = __builtin_amdgcn_mfma_f32_16x16x32_bf16(u1.s, w2f[1][nt], acc[nt], 0,0,0);
        }
        float adjv[4];
        #pragma unroll
        for (int r = 0; r < 4; r++) adjv[r] = sAdj[(quad*4 + r)*JPW + jl];
        #pragma unroll
        for (int nt = 0; nt < 4; nt++)
          #pragma unroll
          for (int r = 0; r < 4; r++)
            agg[nt][r] += adjv[r] * fast_tanh(acc[nt][r] + b2v[nt]);
    }
    #pragma unroll
    for (int nt = 0; nt < 4; nt++)
      #pragma unroll
      for (int r = 0; r < 4; r++)
        sAgg[w*1088 + (quad*4 + r)*68 + nt*16 + col] = agg[nt][r];
    __syncthreads();
    {
        int i = tid >> 4, k4 = (tid & 15) * 4;
        floatx4 s0 = *(const floatx4*)&sAgg[0*1088 + i*68 + k4];
        floatx4 s1 = *(const floatx4*)&sAgg[1*1088 + i*68 + k4];
        floatx4 s2 = *(const floatx4*)&sAgg[2*1088 + i*68 + k4];
        floatx4 s3 = *(const floatx4*)&sAgg[3*1088 + i*68 + k4];
        floatx4 o = (s0 + s1) + (s2 + s3);
        o = o * (1.f/96.f);
        astore4(&partial[((js*BSZ + b)*NN + it*16 + i)*64 + k4], o);
    }
    if (t == TSTEP - 1) return;           // k_out performs the final GRU

    __syncthreads();                      // drains each wave's agent stores (vmcnt 0)
    if (tid == 0) {
        int old = atomicAdd(&cnt[t*(BSZ*ITILES) + b*ITILES + it], 1);
        sLast = (old == JSPLIT - 1);
    }
    __syncthreads();
    if (!sLast) return;

    // ------------------- winner GRU for tile (b, it) ------------------------
    float* sM = lds;          // 16*68 = 1088
    float* sG = lds + 1088;   // 3*1088 = 3264
    float* sH = lds + 4352;   // 16*64 = 1024
    float* sE = lds + 5376;   // 192

    const short8* wzb = (const short8*)wswz;
    short8 fG[8], fSR[8];
    if (w < 3) {
        #pragma unroll
        for (int q = 0; q < 8; q++) fG[q] = wzb[(1 + w)*512 + q*64 + l];
    }
    if (w < 2) {
        #pragma unroll
        for (int q = 0; q < 8; q++) fSR[q] = wzb[(4 + w)*512 + q*64 + l];
    }

    {   // phase A: reduce 8 partials (agent loads), fetch h_old + E rows
        int i = tid >> 4, k4 = (tid & 15) * 4;
        floatx4 a = {0.f,0.f,0.f,0.f};
        #pragma unroll
        for (int p = 0; p < JSPLIT; p++)
            a += aload4(&partial[((p*BSZ + b)*NN + it*16 + i)*64 + k4]);
        *(floatx4*)&sM[i*68 + k4] = a;
        *(floatx4*)&sH[i*64 + k4] = *(const floatx4*)&hprev[(b*NN + it*16 + i)*64 + k4];
    }
    if (tid < 192) {
        int s = skills[b*13 + t];
        sE[tid] = Ef[(tid >> 6)*6144 + s*64 + (tid & 63)];
    }
    __syncthreads();

    // phase B: gate matmuls (wave w -> Whr, Whi, Whh)
    if (w < 3) {
        short8 a0, a1;
        buildA(sM, col, quad, a0, a1);
        floatx4 acc[4];
        zero4(acc);
        mm16r(a0, a1, fG, acc);
        #pragma unroll
        for (int nt = 0; nt < 4; nt++)
          #pragma unroll
          for (int r = 0; r < 4; r++)
            sG[w*1088 + (quad*4 + r)*68 + nt*16 + col] = acc[nt][r];
    }
    __syncthreads();

    // phase C: elementwise GRU, hnew -> sM + hcur
    {
        int i = tid >> 4, k4 = (tid & 15) * 4;
        float h[4];
        #pragma unroll
        for (int e = 0; e < 4; e++) {
            int d = k4 + e;
            float gr = fast_sigmoid(sE[d]       + sG[0*1088 + i*68 + d]);
            float gi = fast_sigmoid(sE[64 + d]  + sG[1*1088 + i*68 + d]);
            float nv = fast_tanh  (sE[128 + d] + gr * sG[2*1088 + i*68 + d]);
            h[e] = (1.f - gi)*nv + gi*sH[i*64 + d];
        }
        #pragma unroll
        for (int e = 0; e < 4; e++) sM[i*68 + k4 + e] = h[e];
        floatx4 hv = { h[0], h[1], h[2], h[3] };
        *(floatx4*)&hcur[(b*NN + it*16 + i)*64 + k4] = hv;
    }
    __syncthreads();

    // phase D: S (wave 0) and R (wave 1) matmuls for next step (ping-pong)
    if (w < 2) {
        short8 a0, a1;
        buildA(sM, col, quad, a0, a1);
        floatx4 acc[4];
        zero4(acc);
        mm16r(a0, a1, fSR, acc);
        float* dst = (w == 0) ? Swrite : Rwrite;
        #pragma unroll
        for (int nt = 0; nt < 4; nt++)
          #pragma unroll
          for (int r = 0; r < 4; r++)
            dst[(b*NN + it*16 + quad*4 + r)*64 + nt*16 + col] = acc[nt][r];
    }
}

// ---------------------------------------------------------------------------
// batched output MLP over all steps: 1152 independent 16-row tiles, 4 waves
// per block. ts==11 waves first compute h(12) from partial(t=11) + h(11).
// grid 288 x 256 threads.
// ---------------------------------------------------------------------------
__global__ __launch_bounds__(256) void k_out(
    const int* __restrict__ skills, const float* __restrict__ partial,
    const float* __restrict__ Ef, const float* __restrict__ hall,
    const ushort_t* __restrict__ wswz,
    const float* __restrict__ bo1, const float* __restrict__ bo2, const float* __restrict__ bo3,
    float* __restrict__ out)
{
    __shared__ float sT[4][16*68];
    int tid = threadIdx.x; int w = tid >> 6; int l = tid & 63;
    int quad = l >> 4, col = l & 15;
    int g = blockIdx.x*4 + w;
    int ts = g / 96; int rem = g % 96; int b = rem / 6, it = rem % 6;
    float* sm = sT[w];

    if (ts < 11) {
        const float* hsrc = hall + (size_t)(ts + 1)*HSLOT + (b*NN + it*16)*64;
        int i = l >> 2, c0 = (l & 3)*16;
        #pragma unroll
        for (int cc = 0; cc < 4; cc++)
            *(floatx4*)&sm[i*68 + c0 + cc*4] = *(const floatx4*)&hsrc[i*64 + c0 + cc*4];
    } else {
        // final GRU: reduce 8 partials into sm, gates, elementwise vs h(11)
        int i = l >> 2, c0 = (l & 3)*16;
        floatx4 a[4]; zero4(a);
        for (int p = 0; p < JSPLIT; p++) {
            const float* base = &partial[((p*BSZ + b)*NN + it*16 + i)*64 + c0];
            #pragma unroll
            for (int cc = 0; cc < 4; cc++) a[cc] += *(const floatx4*)&base[cc*4];
        }
        #pragma unroll
        for (int cc = 0; cc < 4; cc++) *(floatx4*)&sm[i*68 + c0 + cc*4] = a[cc];

        short8 a0, a1; buildA(sm, col, quad, a0, a1);
        floatx4 Ar[4], Ai[4], Ah[4];
        zero4(Ar); zero4(Ai); zero4(Ah);
        mm16(a0, a1, (const short8*)wswz + 1*512, l, Ar);
        mm16(a0, a1, (const short8*)wswz + 2*512, l, Ai);
        mm16(a0, a1, (const short8*)wswz + 3*512, l, Ah);
        int s = skills[b*13 + 11];
        const float* hp = hall + 11*(size_t)HSLOT;
        #pragma unroll
        for (int nt = 0; nt < 4; nt++) {
            int d = nt*16 + col;
            float er = Ef[0*6144 + s*64 + d];
            float ei = Ef[1*6144 + s*64 + d];
            float en = Ef[2*6144 + s*64 + d];
            #pragma unroll
            for (int r = 0; r < 4; r++) {
                int row = it*16 + quad*4 + r;
                float gr = fast_sigmoid(er + Ar[nt][r]);
                float gi = fast_sigmoid(ei + Ai[nt][r]);
                float nv = fast_tanh  (en + gr*Ah[nt][r]);
                sm[(quad*4 + r)*68 + d] = (1.f - gi)*nv + gi*hp[(b*NN + row)*64 + d];
            }
        }
    }

    float bv1[4], bv2[4], bv3[4];
    #pragma unroll
    for (int nt = 0; nt < 4; nt++) {
        bv1[nt] = bo1[nt*16 + col];
        bv2[nt] = bo2[nt*16 + col];
        bv3[nt] = bo3[nt*16 + col];
    }
    short8 a0, a1;
    floatx4 acc[4];

    buildA(sm, col, quad, a0, a1);
    zero4(acc);
    mm16(a0, a1, (const short8*)wswz + 6*512, l, acc);
    #pragma unroll
    for (int nt = 0; nt < 4; nt++)
      #pragma unroll
      for (int r = 0; r < 4; r++)
        sm[(quad*4 + r)*68 + nt*16 + col] = fmaxf(0.f, acc[nt][r] + bv1[nt]);

    buildA(sm, col, quad, a0, a1);
    zero4(acc);
    mm16(a0, a1, (const short8*)wswz + 7*512, l, acc);
    #pragma unroll
    for (int nt = 0; nt < 4; nt++)
      #pragma unroll
      for (int r = 0; r < 4; r++)
        sm[(quad*4 + r)*68 + nt*16 + col] = fmaxf(0.f, acc[nt][r] + bv2[nt]);

    buildA(sm, col, quad, a0, a1);
    zero4(acc);
    mm16(a0, a1, (const short8*)wswz + 8*512, l, acc);
    #pragma unroll
    for (int nt = 0; nt < 4; nt++)
      #pragma unroll
      for (int r = 0; r < 4; r++)
        out[((b*TSTEP + ts)*NN + it*16 + quad*4 + r)*64 + nt*16 + col] = acc[nt][r] + bv3[nt];
}

extern "C" void kernel_launch(void* const* d_in, const int* in_sizes, int n_in,
                              void* d_out, int out_size, void* d_ws, size_t ws_size,
                              hipStream_t stream) {
    const int*   skills = (const int*)d_in[0];
    const float* adj    = (const float*)d_in[1];
    const float* emb    = (const float*)d_in[2];
    const float* Wmsg1  = (const float*)d_in[3];
    const float* b1     = (const float*)d_in[4];
    const float* Wmsg2  = (const float*)d_in[5];
    const float* b2     = (const float*)d_in[6];
    const float* Whr    = (const float*)d_in[7];
    const float* Whi    = (const float*)d_in[8];
    const float* Whh    = (const float*)d_in[9];
    const float* Wir    = (const float*)d_in[10];
    const float* bir    = (const float*)d_in[11];
    const float* Wii    = (const float*)d_in[12];
    const float* bii    = (const float*)d_in[13];
    const float* Win    = (const float*)d_in[14];
    const float* bin    = (const float*)d_in[15];
    const float* Wo1    = (const float*)d_in[16];
    const float* bo1    = (const float*)d_in[17];
    const float* Wo2    = (const float*)d_in[18];
    const float* bo2    = (const float*)d_in[19];
    const float* Wo3    = (const float*)d_in[20];
    const float* bo3    = (const float*)d_in[21];

    char* ws = (char*)d_ws;
    float*    hall    = (float*)(ws + OFF_HALL);
    float*    Ef      = (float*)(ws + OFF_E);
    float*    S0      = (float*)(ws + OFF_S0);
    float*    S1      = (float*)(ws + OFF_S1);
    float*    R0      = (float*)(ws + OFF_R0);
    float*    R1      = (float*)(ws + OFF_R1);
    float*    partial = (float*)(ws + OFF_PART);
    ushort_t* wswz    = (ushort_t*)(ws + OFF_WSWZ);
    int*      cnt     = (int*)(ws + OFF_CNT);
    float*    out     = (float*)d_out;

    k_init<<<dim3(216), dim3(256), 0, stream>>>(emb, Wmsg1, Wmsg2, Whr, Whi, Whh,
        Wir, bir, Wii, bii, Win, bin, Wo1, Wo2, Wo3, cnt, Ef, wswz);

    k_step0<<<dim3(BSZ*ITILES), dim3(256), 0, stream>>>(
        adj, b1, b2, skills, Ef, wswz, hall, S1, R1);

    for (int t = 1; t < TSTEP; t++) {
        const float* Sr = (t & 1) ? S1 : S0;
        const float* Rr = (t & 1) ? R1 : R0;
        float*       Sw = (t & 1) ? S0 : S1;
        float*       Rw = (t & 1) ? R0 : R1;
        k_step<<<dim3(JSPLIT*BSZ*ITILES), dim3(256), 0, stream>>>(
            adj, b1, b2, Sr, Rr, wswz, partial, skills, Ef,
            hall + (size_t)t*HSLOT, hall + (size_t)(t+1)*HSLOT,
            Sw, Rw, cnt, t);
    }
    k_out<<<dim3(288), dim3(256), 0, stream>>>(skills, partial, Ef, hall, wswz,
        bo1, bo2, bo3, out);
}